// Round 6
// baseline (211.846 us; speedup 1.0000x reference)
//
#include <hip/hip_runtime.h>
#include <math.h>

#define G 4
#define NN 1024
#define FF 256
#define HH 256
#define BB 32
#define LL 4

typedef __attribute__((ext_vector_type(8))) short short8;
typedef __attribute__((ext_vector_type(8))) unsigned short ushort8;
typedef __attribute__((ext_vector_type(4))) unsigned short ushort4v;
typedef __attribute__((ext_vector_type(4))) float floatx4;

__device__ inline unsigned short f2bf(float f) {
  union { float f; unsigned u; } x; x.f = f;
  unsigned r = x.u + 0x7fffu + ((x.u >> 16) & 1u);  // RNE
  return (unsigned short)(r >> 16);
}
__device__ inline float bf2f(unsigned short u) {
  union { unsigned u; float f; } x; x.u = (unsigned)u << 16;
  return x.f;
}

// ---- in tile: x0 = relu(X @ w_in + b_in) -> xbf + h0bf (both bf16 [m][n])
// [R0-verified]
__device__ void in_tile(int job, const float* __restrict__ X,
                        const float* __restrict__ w_in,
                        const float* __restrict__ b_in,
                        unsigned short* __restrict__ xbf,
                        unsigned short* __restrict__ h0bf, unsigned short* As,
                        unsigned short* Bs, int t) {
  const int nt_ = job & 3, mt = (job >> 2) & 15, g = job >> 6;
  const int m0 = mt * 64, n0 = nt_ * 64;
  const int lane = t & 63, w = t >> 6;
  const int wm = w & 1, wn = w >> 1;
  const int l16 = lane & 15, quad = lane >> 4;

  floatx4 acc[2][2];
#pragma unroll
  for (int i = 0; i < 2; ++i)
#pragma unroll
    for (int j = 0; j < 2; ++j) acc[i][j] = (floatx4){0.f, 0.f, 0.f, 0.f};

  for (int tt = 0; tt < 4; ++tt) {
    const int kb = tt * 64;
    __syncthreads();
#pragma unroll
    for (int i = 0; i < 2; ++i) {
      const int q = t + i * 256;
      const int row = q >> 3, c8 = q & 7;
      const float* Af =
          X + (long)g * NN * FF + (long)(m0 + row) * FF + kb + c8 * 8;
      float4 f0 = *(const float4*)Af;
      float4 f1 = *(const float4*)(Af + 4);
      ushort8 v;
      v[0] = f2bf(f0.x); v[1] = f2bf(f0.y); v[2] = f2bf(f0.z); v[3] = f2bf(f0.w);
      v[4] = f2bf(f1.x); v[5] = f2bf(f1.y); v[6] = f2bf(f1.z); v[7] = f2bf(f1.w);
      *(ushort8*)&As[row * 72 + c8 * 8] = v;
    }
    {  // w_in fp32 [k][n] -> Bs[n][k] (LDS transpose)
      const int row = t >> 2;
      const int c0 = (t & 3) * 16;
#pragma unroll
      for (int j = 0; j < 4; ++j) {
        float4 f = *(const float4*)&w_in[(long)(kb + row) * HH + n0 + c0 + j * 4];
        Bs[(c0 + j * 4 + 0) * 72 + row] = f2bf(f.x);
        Bs[(c0 + j * 4 + 1) * 72 + row] = f2bf(f.y);
        Bs[(c0 + j * 4 + 2) * 72 + row] = f2bf(f.z);
        Bs[(c0 + j * 4 + 3) * 72 + row] = f2bf(f.w);
      }
    }
    __syncthreads();
#pragma unroll
    for (int kk = 0; kk < 64; kk += 32) {
      const int ko = kk + quad * 8;
      short8 a0 = *(const short8*)&As[(wm * 32 + l16) * 72 + ko];
      short8 a1 = *(const short8*)&As[(wm * 32 + 16 + l16) * 72 + ko];
      short8 b0 = *(const short8*)&Bs[(wn * 32 + l16) * 72 + ko];
      short8 b1 = *(const short8*)&Bs[(wn * 32 + 16 + l16) * 72 + ko];
      acc[0][0] = __builtin_amdgcn_mfma_f32_16x16x32_bf16(a0, b0, acc[0][0], 0, 0, 0);
      acc[0][1] = __builtin_amdgcn_mfma_f32_16x16x32_bf16(a0, b1, acc[0][1], 0, 0, 0);
      acc[1][0] = __builtin_amdgcn_mfma_f32_16x16x32_bf16(a1, b0, acc[1][0], 0, 0, 0);
      acc[1][1] = __builtin_amdgcn_mfma_f32_16x16x32_bf16(a1, b1, acc[1][1], 0, 0, 0);
    }
  }

#pragma unroll
  for (int i = 0; i < 2; ++i) {
#pragma unroll
    for (int j = 0; j < 2; ++j) {
      const int n = n0 + wn * 32 + j * 16 + l16;
      const int mB = m0 + wm * 32 + i * 16 + quad * 4;
      const float bv = b_in[n];
#pragma unroll
      for (int r = 0; r < 4; ++r) {
        const unsigned short pv = f2bf(fmaxf(acc[i][j][r] + bv, 0.f));
        xbf[(long)g * NN * HH + (long)(mB + r) * HH + n] = pv;
        h0bf[(long)g * NN * HH + (long)(mB + r) * HH + n] = pv;
      }
    }
  }
}

// ---- misc jobs [R0-verified] ----
__device__ void mask_job(int b, const void* __restrict__ cp_mask,
                         float* __restrict__ fmask, float* __restrict__ denom,
                         int t) {
  const unsigned char* bytes = (const unsigned char*)cp_mask;
  __shared__ int fmt;
  __shared__ float red[256];
  if (t == 0) {
    int any = 0;
    for (int i = 0; i < 256; ++i)
      if ((i & 3) && bytes[i]) any = 1;
    fmt = any ? 0 : 1;
  }
  __syncthreads();
  float cnt = 0.f;
  for (int n = t; n < NN; n += 256) {
    float v;
    if (fmt)
      v = ((const int*)cp_mask)[b * NN + n] ? 1.f : 0.f;
    else
      v = bytes[b * NN + n] ? 1.f : 0.f;
    fmask[b * NN + n] = v;
    cnt += v;
  }
  red[t] = cnt;
  __syncthreads();
  for (int s = 128; s > 0; s >>= 1) {
    if (t < s) red[t] += red[t + s];
    __syncthreads();
  }
  if (t == 0) denom[b] = fmaxf(red[0], 1.f);
}

__device__ void gw_job(int j, const float* __restrict__ gcn_w,
                       unsigned short* __restrict__ gwT, int t) {
  const int l = j >> 4, r0 = (j & 15) * 16;
  const float* src = gcn_w + (long)l * HH * HH;
  unsigned short* dst = gwT + (long)l * HH * HH;
  unsigned short vv[16];
#pragma unroll
  for (int rr = 0; rr < 16; ++rr) vv[rr] = f2bf(src[(long)(r0 + rr) * HH + t]);
  *(ushort8*)&dst[(long)t * HH + r0] = *(ushort8*)&vv[0];
  *(ushort8*)&dst[(long)t * HH + r0 + 8] = *(ushort8*)&vv[8];
}

// ---------------------------------------------------------------------------
// pre_kernel [R0-verified]: [0,1024) A fp32->bf16 (16 el/thr);
// [1024,1280) input GEMM; [1280,1344) gwT; [1344,1376) mask; 1376 zero-out.
// 18.4 KB LDS -> high occupancy for the streaming branches.
// ---------------------------------------------------------------------------
__global__ __launch_bounds__(256) void pre_kernel(
    const float* __restrict__ batch_as, unsigned short* __restrict__ Abf,
    const float* __restrict__ batch_xs, const float* __restrict__ w_in,
    const float* __restrict__ b_in, unsigned short* __restrict__ xbf,
    unsigned short* __restrict__ h0bf, const float* __restrict__ gcn_w,
    unsigned short* __restrict__ gwT, const void* __restrict__ cp_mask,
    float* __restrict__ fmask, float* __restrict__ denom,
    float* __restrict__ out) {
  __shared__ __align__(16) unsigned short As[64 * 72];
  __shared__ __align__(16) unsigned short Bs[64 * 72];
  const int b = blockIdx.x, t = threadIdx.x;
  if (b < 1024) {
    const long idx = ((long)b * 256 + t) * 16;
#pragma unroll
    for (int h = 0; h < 2; ++h) {
      float4 f0 = *(const float4*)&batch_as[idx + h * 8];
      float4 f1 = *(const float4*)&batch_as[idx + h * 8 + 4];
      ushort8 v;
      v[0] = f2bf(f0.x); v[1] = f2bf(f0.y); v[2] = f2bf(f0.z); v[3] = f2bf(f0.w);
      v[4] = f2bf(f1.x); v[5] = f2bf(f1.y); v[6] = f2bf(f1.z); v[7] = f2bf(f1.w);
      *(ushort8*)&Abf[idx + h * 8] = v;
    }
  } else if (b < 1280) {
    in_tile(b - 1024, batch_xs, w_in, b_in, xbf, h0bf, As, Bs, t);
  } else if (b < 1344) {
    gw_job(b - 1280, gcn_w, gwT, t);
  } else if (b < 1376) {
    mask_job(b - 1344, cp_mask, fmask, denom, t);
  } else {
    for (int i = 0; i < 32; ++i) out[i * 256 + t] = 0.f;
  }
}

// ---------------------------------------------------------------------------
// g1_nolds: yT = (x @ W_l)^T. 64x64 tile, NO LDS, NO barriers.
// MFMA fragments loaded straight from global (L2-resident operands: x 2 MB,
// W 128 KB).  Fragment k-mapping identical to the verified LDS version:
// As[row][kk+quad*8] -> x[grow][kk+quad*8].
// ---------------------------------------------------------------------------
__global__ __launch_bounds__(256) void g1_nolds(
    const unsigned short* __restrict__ xbf,
    const unsigned short* __restrict__ WT,
    unsigned short* __restrict__ yT) {
  const int n0 = blockIdx.x * 64;
  const int m0 = blockIdx.y * 64;
  const int g = blockIdx.z;
  const int t = threadIdx.x;
  const int lane = t & 63, w = t >> 6;
  const int wm = w & 1, wn = w >> 1;
  const int l16 = lane & 15, quad = lane >> 4;

  const unsigned short* Ar0 =
      xbf + (long)g * NN * HH + (long)(m0 + wm * 32 + l16) * HH + quad * 8;
  const unsigned short* Ar1 = Ar0 + 16 * HH;
  const unsigned short* Br0 = WT + (long)(n0 + wn * 32 + l16) * HH + quad * 8;
  const unsigned short* Br1 = Br0 + 16 * HH;

  floatx4 acc[2][2];
#pragma unroll
  for (int i = 0; i < 2; ++i)
#pragma unroll
    for (int j = 0; j < 2; ++j) acc[i][j] = (floatx4){0.f, 0.f, 0.f, 0.f};

#pragma unroll
  for (int kk = 0; kk < HH; kk += 32) {
    short8 a0 = *(const short8*)(Ar0 + kk);
    short8 a1 = *(const short8*)(Ar1 + kk);
    short8 b0 = *(const short8*)(Br0 + kk);
    short8 b1 = *(const short8*)(Br1 + kk);
    acc[0][0] = __builtin_amdgcn_mfma_f32_16x16x32_bf16(a0, b0, acc[0][0], 0, 0, 0);
    acc[0][1] = __builtin_amdgcn_mfma_f32_16x16x32_bf16(a0, b1, acc[0][1], 0, 0, 0);
    acc[1][0] = __builtin_amdgcn_mfma_f32_16x16x32_bf16(a1, b0, acc[1][0], 0, 0, 0);
    acc[1][1] = __builtin_amdgcn_mfma_f32_16x16x32_bf16(a1, b1, acc[1][1], 0, 0, 0);
  }

#pragma unroll
  for (int i = 0; i < 2; ++i) {
#pragma unroll
    for (int j = 0; j < 2; ++j) {
      const int n = n0 + wn * 32 + j * 16 + l16;
      const int mB = m0 + wm * 32 + i * 16 + quad * 4;
      ushort4v pv;
#pragma unroll
      for (int r = 0; r < 4; ++r) pv[r] = f2bf(acc[i][j][r]);
      *(ushort4v*)&yT[(long)g * HH * NN + (long)n * NN + mB] = pv;
    }
  }
}

// ---------------------------------------------------------------------------
// g2_nolds<ACT>: T = A @ y. 32x64 tile, K=1024, NO LDS, NO barriers.
// A-row/B-row fragments stream from global (L2/L3); quads 0..3 cover 64
// contiguous bytes of each row -> full cache-line utilization.
// ACT=1: xbf = relu(T+bias).  ACT=0: tanh + residual + masked mean.
// ---------------------------------------------------------------------------
template <int ACT>
__global__ __launch_bounds__(256) void g2_nolds(
    const unsigned short* __restrict__ Abf,
    const unsigned short* __restrict__ yT, const float* __restrict__ bias,
    const unsigned short* __restrict__ h0bf, unsigned short* __restrict__ xbf,
    const float* __restrict__ fmask, const float* __restrict__ denom,
    const int* __restrict__ gidx, float* __restrict__ out) {
  const int n0 = blockIdx.x * 64;
  const int m0 = blockIdx.y * 32;
  const int g = blockIdx.z;
  const int t = threadIdx.x;
  const int lane = t & 63, w = t >> 6;
  const int wm = w & 1, wn = w >> 1;
  const int l16 = lane & 15, quad = lane >> 4;

  const unsigned short* Ar =
      Abf + (long)g * NN * NN + (long)(m0 + wm * 16 + l16) * NN + quad * 8;
  const unsigned short* Br0 =
      yT + (long)g * HH * NN + (long)(n0 + wn * 32 + l16) * NN + quad * 8;
  const unsigned short* Br1 = Br0 + 16 * NN;

  floatx4 acc[2];
  acc[0] = (floatx4){0.f, 0.f, 0.f, 0.f};
  acc[1] = (floatx4){0.f, 0.f, 0.f, 0.f};

#pragma unroll 4
  for (int kk = 0; kk < NN; kk += 32) {
    short8 a = *(const short8*)(Ar + kk);
    short8 b0 = *(const short8*)(Br0 + kk);
    short8 b1 = *(const short8*)(Br1 + kk);
    acc[0] = __builtin_amdgcn_mfma_f32_16x16x32_bf16(a, b0, acc[0], 0, 0, 0);
    acc[1] = __builtin_amdgcn_mfma_f32_16x16x32_bf16(a, b1, acc[1], 0, 0, 0);
  }

  if (ACT == 1) {
#pragma unroll
    for (int j = 0; j < 2; ++j) {
      const int n = n0 + wn * 32 + j * 16 + l16;
      const int mB = m0 + wm * 16 + quad * 4;
      const float bv = bias[n];
#pragma unroll
      for (int r = 0; r < 4; ++r)
        xbf[(long)g * NN * HH + (long)(mB + r) * HH + n] =
            f2bf(fmaxf(acc[j][r] + bv, 0.f));
    }
  } else {
    const int mB0 = m0 + wm * 16 + quad * 4;
    float zv[2][4];
#pragma unroll
    for (int j = 0; j < 2; ++j) {
      const int n = n0 + wn * 32 + j * 16 + l16;
      const float bv = bias[n];
#pragma unroll
      for (int r = 0; r < 4; ++r) {
        const long idx = (long)g * NN * HH + (long)(mB0 + r) * HH + n;
        zv[j][r] = tanhf(acc[j][r] + bv) + bf2f(h0bf[idx]);
      }
    }
    for (int b = 0; b < BB; ++b) {
      if (gidx[b] != g) continue;  // block-uniform branch
      const float invd = 1.f / denom[b];
      float m4[4];
#pragma unroll
      for (int r = 0; r < 4; ++r) m4[r] = fmask[b * NN + mB0 + r];
#pragma unroll
      for (int j = 0; j < 2; ++j) {
        float p = m4[0] * zv[j][0] + m4[1] * zv[j][1] + m4[2] * zv[j][2] +
                  m4[3] * zv[j][3];
        p += __shfl_xor(p, 16);
        p += __shfl_xor(p, 32);
        if (quad == 0) {
          const int n = n0 + wn * 32 + j * 16 + l16;
          atomicAdd(&out[b * HH + n], p * invd);
        }
      }
    }
  }
}

extern "C" void kernel_launch(void* const* d_in, const int* in_sizes, int n_in,
                              void* d_out, int out_size, void* d_ws,
                              size_t ws_size, hipStream_t stream) {
  (void)in_sizes; (void)n_in; (void)out_size; (void)ws_size;
  const float* batch_xs = (const float*)d_in[0];
  const float* batch_as = (const float*)d_in[1];
  const float* w_in = (const float*)d_in[2];
  const float* b_in = (const float*)d_in[3];
  const float* gcn_w = (const float*)d_in[4];
  const float* gcn_b = (const float*)d_in[5];
  const int* graph_idx = (const int*)d_in[6];
  const void* cp_mask = d_in[7];
  float* out = (float*)d_out;

  char* p = (char*)d_ws;
  unsigned short* Abf = (unsigned short*)p;  p += (long)G * NN * NN * 2;
  unsigned short* gwT = (unsigned short*)p;  p += (long)LL * HH * HH * 2;
  unsigned short* xbf = (unsigned short*)p;  p += (long)G * NN * HH * 2;
  unsigned short* h0bf = (unsigned short*)p; p += (long)G * NN * HH * 2;
  unsigned short* yTa = (unsigned short*)p;  p += (long)G * HH * NN * 2;
  unsigned short* yTb = (unsigned short*)p;  p += (long)G * HH * NN * 2;
  float* fmask = (float*)p;                  p += (long)BB * NN * 4;
  float* denom = (float*)p;                  p += BB * 4;

  pre_kernel<<<1377, 256, 0, stream>>>(batch_as, Abf, batch_xs, w_in, b_in,
                                       xbf, h0bf, gcn_w, gwT, cp_mask, fmask,
                                       denom, out);

  // y0 = x0 @ W0
  g1_nolds<<<dim3(4, 16, G), 256, 0, stream>>>(xbf, gwT, yTa);

  for (int l = 0; l < LL; ++l) {
    const unsigned short* ycur = (l & 1) ? yTb : yTa;
    unsigned short* ynext = (l & 1) ? yTa : yTb;
    if (l < LL - 1) {
      // x_{l+1} = relu(A@y_l + b_l)
      g2_nolds<1><<<dim3(4, 32, G), 256, 0, stream>>>(
          Abf, ycur, gcn_b + (long)l * HH, nullptr, xbf, nullptr, nullptr,
          nullptr, nullptr);
      // y_{l+1} = x_{l+1} @ W_{l+1}
      g1_nolds<<<dim3(4, 16, G), 256, 0, stream>>>(
          xbf, gwT + (long)(l + 1) * HH * HH, ynext);
    } else {
      // final: tanh(A@y3 + b3) + h0, masked mean
      g2_nolds<0><<<dim3(4, 32, G), 256, 0, stream>>>(
          Abf, ycur, gcn_b + (long)l * HH, h0bf, nullptr, fmask, denom,
          graph_idx, out);
    }
  }
}

// Round 7
// 149.392 us; speedup vs baseline: 1.4181x; 1.4181x over previous
//
#include <hip/hip_runtime.h>
#include <math.h>

#define G 4
#define NN 1024
#define FF 256
#define HH 256
#define BB 32
#define LL 4

typedef __attribute__((ext_vector_type(8))) short short8;
typedef __attribute__((ext_vector_type(8))) unsigned short ushort8;
typedef __attribute__((ext_vector_type(4))) unsigned short ushort4v;
typedef __attribute__((ext_vector_type(4))) float floatx4;

__device__ inline unsigned short f2bf(float f) {
  union { float f; unsigned u; } x; x.f = f;
  unsigned r = x.u + 0x7fffu + ((x.u >> 16) & 1u);  // RNE
  return (unsigned short)(r >> 16);
}
__device__ inline float bf2f(unsigned short u) {
  union { unsigned u; float f; } x; x.u = (unsigned)u << 16;
  return x.f;
}

// ---- in tile: x0 = relu(X @ w_in + b_in) -> xbf + h0bf (both bf16 [m][n])
// [R0-verified]
__device__ void in_tile(int job, const float* __restrict__ X,
                        const float* __restrict__ w_in,
                        const float* __restrict__ b_in,
                        unsigned short* __restrict__ xbf,
                        unsigned short* __restrict__ h0bf, unsigned short* As,
                        unsigned short* Bs, int t) {
  const int nt_ = job & 3, mt = (job >> 2) & 15, g = job >> 6;
  const int m0 = mt * 64, n0 = nt_ * 64;
  const int lane = t & 63, w = t >> 6;
  const int wm = w & 1, wn = w >> 1;
  const int l16 = lane & 15, quad = lane >> 4;

  floatx4 acc[2][2];
#pragma unroll
  for (int i = 0; i < 2; ++i)
#pragma unroll
    for (int j = 0; j < 2; ++j) acc[i][j] = (floatx4){0.f, 0.f, 0.f, 0.f};

  for (int tt = 0; tt < 4; ++tt) {
    const int kb = tt * 64;
    __syncthreads();
#pragma unroll
    for (int i = 0; i < 2; ++i) {
      const int q = t + i * 256;
      const int row = q >> 3, c8 = q & 7;
      const float* Af =
          X + (long)g * NN * FF + (long)(m0 + row) * FF + kb + c8 * 8;
      float4 f0 = *(const float4*)Af;
      float4 f1 = *(const float4*)(Af + 4);
      ushort8 v;
      v[0] = f2bf(f0.x); v[1] = f2bf(f0.y); v[2] = f2bf(f0.z); v[3] = f2bf(f0.w);
      v[4] = f2bf(f1.x); v[5] = f2bf(f1.y); v[6] = f2bf(f1.z); v[7] = f2bf(f1.w);
      *(ushort8*)&As[row * 72 + c8 * 8] = v;
    }
    {  // w_in fp32 [k][n] -> Bs[n][k] (LDS transpose)
      const int row = t >> 2;
      const int c0 = (t & 3) * 16;
#pragma unroll
      for (int j = 0; j < 4; ++j) {
        float4 f = *(const float4*)&w_in[(long)(kb + row) * HH + n0 + c0 + j * 4];
        Bs[(c0 + j * 4 + 0) * 72 + row] = f2bf(f.x);
        Bs[(c0 + j * 4 + 1) * 72 + row] = f2bf(f.y);
        Bs[(c0 + j * 4 + 2) * 72 + row] = f2bf(f.z);
        Bs[(c0 + j * 4 + 3) * 72 + row] = f2bf(f.w);
      }
    }
    __syncthreads();
#pragma unroll
    for (int kk = 0; kk < 64; kk += 32) {
      const int ko = kk + quad * 8;
      short8 a0 = *(const short8*)&As[(wm * 32 + l16) * 72 + ko];
      short8 a1 = *(const short8*)&As[(wm * 32 + 16 + l16) * 72 + ko];
      short8 b0 = *(const short8*)&Bs[(wn * 32 + l16) * 72 + ko];
      short8 b1 = *(const short8*)&Bs[(wn * 32 + 16 + l16) * 72 + ko];
      acc[0][0] = __builtin_amdgcn_mfma_f32_16x16x32_bf16(a0, b0, acc[0][0], 0, 0, 0);
      acc[0][1] = __builtin_amdgcn_mfma_f32_16x16x32_bf16(a0, b1, acc[0][1], 0, 0, 0);
      acc[1][0] = __builtin_amdgcn_mfma_f32_16x16x32_bf16(a1, b0, acc[1][0], 0, 0, 0);
      acc[1][1] = __builtin_amdgcn_mfma_f32_16x16x32_bf16(a1, b1, acc[1][1], 0, 0, 0);
    }
  }

#pragma unroll
  for (int i = 0; i < 2; ++i) {
#pragma unroll
    for (int j = 0; j < 2; ++j) {
      const int n = n0 + wn * 32 + j * 16 + l16;
      const int mB = m0 + wm * 32 + i * 16 + quad * 4;
      const float bv = b_in[n];
#pragma unroll
      for (int r = 0; r < 4; ++r) {
        const unsigned short pv = f2bf(fmaxf(acc[i][j][r] + bv, 0.f));
        xbf[(long)g * NN * HH + (long)(mB + r) * HH + n] = pv;
        h0bf[(long)g * NN * HH + (long)(mB + r) * HH + n] = pv;
      }
    }
  }
}

// ---- misc jobs [R0-verified] ----
__device__ void mask_job(int b, const void* __restrict__ cp_mask,
                         float* __restrict__ fmask, float* __restrict__ denom,
                         int t) {
  const unsigned char* bytes = (const unsigned char*)cp_mask;
  __shared__ int fmt;
  __shared__ float red[256];
  if (t == 0) {
    int any = 0;
    for (int i = 0; i < 256; ++i)
      if ((i & 3) && bytes[i]) any = 1;
    fmt = any ? 0 : 1;
  }
  __syncthreads();
  float cnt = 0.f;
  for (int n = t; n < NN; n += 256) {
    float v;
    if (fmt)
      v = ((const int*)cp_mask)[b * NN + n] ? 1.f : 0.f;
    else
      v = bytes[b * NN + n] ? 1.f : 0.f;
    fmask[b * NN + n] = v;
    cnt += v;
  }
  red[t] = cnt;
  __syncthreads();
  for (int s = 128; s > 0; s >>= 1) {
    if (t < s) red[t] += red[t + s];
    __syncthreads();
  }
  if (t == 0) denom[b] = fmaxf(red[0], 1.f);
}

__device__ void gw_job(int j, const float* __restrict__ gcn_w,
                       unsigned short* __restrict__ gwT, int t) {
  const int l = j >> 4, r0 = (j & 15) * 16;
  const float* src = gcn_w + (long)l * HH * HH;
  unsigned short* dst = gwT + (long)l * HH * HH;
  unsigned short vv[16];
#pragma unroll
  for (int rr = 0; rr < 16; ++rr) vv[rr] = f2bf(src[(long)(r0 + rr) * HH + t]);
  *(ushort8*)&dst[(long)t * HH + r0] = *(ushort8*)&vv[0];
  *(ushort8*)&dst[(long)t * HH + r0 + 8] = *(ushort8*)&vv[8];
}

// ---------------------------------------------------------------------------
// pre_kernel [R0-verified]: [0,1024) A fp32->bf16 (16 el/thr);
// [1024,1280) input GEMM; [1280,1344) gwT; [1344,1376) mask; 1376 zero-out.
// ---------------------------------------------------------------------------
__global__ __launch_bounds__(256) void pre_kernel(
    const float* __restrict__ batch_as, unsigned short* __restrict__ Abf,
    const float* __restrict__ batch_xs, const float* __restrict__ w_in,
    const float* __restrict__ b_in, unsigned short* __restrict__ xbf,
    unsigned short* __restrict__ h0bf, const float* __restrict__ gcn_w,
    unsigned short* __restrict__ gwT, const void* __restrict__ cp_mask,
    float* __restrict__ fmask, float* __restrict__ denom,
    float* __restrict__ out) {
  __shared__ __align__(16) unsigned short As[64 * 72];
  __shared__ __align__(16) unsigned short Bs[64 * 72];
  const int b = blockIdx.x, t = threadIdx.x;
  if (b < 1024) {
    const long idx = ((long)b * 256 + t) * 16;
#pragma unroll
    for (int h = 0; h < 2; ++h) {
      float4 f0 = *(const float4*)&batch_as[idx + h * 8];
      float4 f1 = *(const float4*)&batch_as[idx + h * 8 + 4];
      ushort8 v;
      v[0] = f2bf(f0.x); v[1] = f2bf(f0.y); v[2] = f2bf(f0.z); v[3] = f2bf(f0.w);
      v[4] = f2bf(f1.x); v[5] = f2bf(f1.y); v[6] = f2bf(f1.z); v[7] = f2bf(f1.w);
      *(ushort8*)&Abf[idx + h * 8] = v;
    }
  } else if (b < 1280) {
    in_tile(b - 1024, batch_xs, w_in, b_in, xbf, h0bf, As, Bs, t);
  } else if (b < 1344) {
    gw_job(b - 1280, gcn_w, gwT, t);
  } else if (b < 1376) {
    mask_job(b - 1344, cp_mask, fmask, denom, t);
  } else {
    for (int i = 0; i < 32; ++i) out[i * 256 + t] = 0.f;
  }
}

// ---------------------------------------------------------------------------
// g1: yT = (x @ W_l)^T bf16 [g][n][m]. 64x64 tile, BK=128 (2 K-steps, was 4).
// Same fragment mapping / accumulation order as the verified version.
// ---------------------------------------------------------------------------
__global__ __launch_bounds__(256) void g1_kernel(
    const unsigned short* __restrict__ xbf,
    const unsigned short* __restrict__ WT,
    unsigned short* __restrict__ yT) {
  __shared__ __align__(16) unsigned short As[64 * 136];
  __shared__ __align__(16) unsigned short Bs[64 * 136];
  const int n0 = blockIdx.x * 64;
  const int m0 = blockIdx.y * 64;
  const int g = blockIdx.z;
  const int t = threadIdx.x;
  const int lane = t & 63, w = t >> 6;
  const int wm = w & 1, wn = w >> 1;
  const int l16 = lane & 15, quad = lane >> 4;

  const unsigned short* Ab = xbf + (long)g * NN * HH;

  ushort8 pa[4], pb[4];
  auto load_tile = [&](int tt) {
    const int kb = tt * 128;
#pragma unroll
    for (int i = 0; i < 4; ++i) {  // 64 rows x 128 k = 1024 chunks
      const int q = t + i * 256;
      const int row = q >> 4, c8 = q & 15;
      pa[i] = *(const ushort8*)&Ab[(long)(m0 + row) * HH + kb + c8 * 8];
      pb[i] = *(const ushort8*)&WT[(long)(n0 + row) * HH + kb + c8 * 8];
    }
  };
  auto store_tile = [&]() {
#pragma unroll
    for (int i = 0; i < 4; ++i) {
      const int q = t + i * 256;
      const int row = q >> 4, c8 = q & 15;
      *(ushort8*)&As[row * 136 + c8 * 8] = pa[i];
      *(ushort8*)&Bs[row * 136 + c8 * 8] = pb[i];
    }
  };

  floatx4 acc[2][2];
#pragma unroll
  for (int i = 0; i < 2; ++i)
#pragma unroll
    for (int j = 0; j < 2; ++j) acc[i][j] = (floatx4){0.f, 0.f, 0.f, 0.f};

  load_tile(0);
  for (int tt = 0; tt < 2; ++tt) {
    __syncthreads();
    store_tile();
    __syncthreads();
    if (tt + 1 < 2) load_tile(tt + 1);
#pragma unroll
    for (int kk = 0; kk < 128; kk += 32) {
      const int ko = kk + quad * 8;
      short8 a0 = *(const short8*)&As[(wm * 32 + l16) * 136 + ko];
      short8 a1 = *(const short8*)&As[(wm * 32 + 16 + l16) * 136 + ko];
      short8 b0 = *(const short8*)&Bs[(wn * 32 + l16) * 136 + ko];
      short8 b1 = *(const short8*)&Bs[(wn * 32 + 16 + l16) * 136 + ko];
      acc[0][0] = __builtin_amdgcn_mfma_f32_16x16x32_bf16(a0, b0, acc[0][0], 0, 0, 0);
      acc[0][1] = __builtin_amdgcn_mfma_f32_16x16x32_bf16(a0, b1, acc[0][1], 0, 0, 0);
      acc[1][0] = __builtin_amdgcn_mfma_f32_16x16x32_bf16(a1, b0, acc[1][0], 0, 0, 0);
      acc[1][1] = __builtin_amdgcn_mfma_f32_16x16x32_bf16(a1, b1, acc[1][1], 0, 0, 0);
    }
  }

#pragma unroll
  for (int i = 0; i < 2; ++i) {
#pragma unroll
    for (int j = 0; j < 2; ++j) {
      const int n = n0 + wn * 32 + j * 16 + l16;
      const int mB = m0 + wm * 32 + i * 16 + quad * 4;
      ushort4v pv;
#pragma unroll
      for (int r = 0; r < 4; ++r) pv[r] = f2bf(acc[i][j][r]);
      *(ushort4v*)&yT[(long)g * HH * NN + (long)n * NN + mB] = pv;
    }
  }
}

// ---------------------------------------------------------------------------
// g2<ACT>: T = A @ y. 32x64 tile, BK=256 (4 K-steps, was 8).
// Same fragment mapping / accumulation order as the verified version.
// LDS 50.7 KB -> still 2 blocks/CU (grid-capped at 2 anyway).
// ACT=1: xbf = relu(T+bias).  ACT=0: tanh + residual + masked mean.
// ---------------------------------------------------------------------------
template <int ACT>
__global__ __launch_bounds__(256) void g2_kernel(
    const unsigned short* __restrict__ Abf,
    const unsigned short* __restrict__ yT, const float* __restrict__ bias,
    const unsigned short* __restrict__ h0bf, unsigned short* __restrict__ xbf,
    const float* __restrict__ fmask, const float* __restrict__ denom,
    const int* __restrict__ gidx, float* __restrict__ out) {
  __shared__ __align__(16) unsigned short As[32 * 264];
  __shared__ __align__(16) unsigned short Bs[64 * 264];
  const int n0 = blockIdx.x * 64;
  const int m0 = blockIdx.y * 32;
  const int g = blockIdx.z;
  const int t = threadIdx.x;
  const int lane = t & 63, w = t >> 6;
  const int wm = w & 1, wn = w >> 1;
  const int l16 = lane & 15, quad = lane >> 4;

  const unsigned short* Ag = Abf + (long)g * NN * NN + (long)m0 * NN;
  const unsigned short* Bg = yT + (long)g * HH * NN + (long)n0 * NN;

  ushort8 pa[4], pb[8];
  auto load_tile = [&](int tt) {
    const int kb = tt * 256;
#pragma unroll
    for (int i = 0; i < 4; ++i) {  // A: 32 rows x 256 k = 1024 chunks
      const int q = t + i * 256;
      const int row = q >> 5, c8 = q & 31;
      pa[i] = *(const ushort8*)&Ag[(long)row * NN + kb + c8 * 8];
    }
#pragma unroll
    for (int i = 0; i < 8; ++i) {  // B: 64 rows x 256 k = 2048 chunks
      const int q = t + i * 256;
      const int row = q >> 5, c8 = q & 31;
      pb[i] = *(const ushort8*)&Bg[(long)row * NN + kb + c8 * 8];
    }
  };
  auto store_tile = [&]() {
#pragma unroll
    for (int i = 0; i < 4; ++i) {
      const int q = t + i * 256;
      const int row = q >> 5, c8 = q & 31;
      *(ushort8*)&As[row * 264 + c8 * 8] = pa[i];
    }
#pragma unroll
    for (int i = 0; i < 8; ++i) {
      const int q = t + i * 256;
      const int row = q >> 5, c8 = q & 31;
      *(ushort8*)&Bs[row * 264 + c8 * 8] = pb[i];
    }
  };

  floatx4 acc[2];
  acc[0] = (floatx4){0.f, 0.f, 0.f, 0.f};
  acc[1] = (floatx4){0.f, 0.f, 0.f, 0.f};

  load_tile(0);
  for (int tt = 0; tt < 4; ++tt) {
    __syncthreads();
    store_tile();
    __syncthreads();
    if (tt + 1 < 4) load_tile(tt + 1);
#pragma unroll
    for (int kk = 0; kk < 256; kk += 32) {
      const int ko = kk + quad * 8;
      short8 a = *(const short8*)&As[(wm * 16 + l16) * 264 + ko];
      short8 b0 = *(const short8*)&Bs[(wn * 32 + l16) * 264 + ko];
      short8 b1 = *(const short8*)&Bs[(wn * 32 + 16 + l16) * 264 + ko];
      acc[0] = __builtin_amdgcn_mfma_f32_16x16x32_bf16(a, b0, acc[0], 0, 0, 0);
      acc[1] = __builtin_amdgcn_mfma_f32_16x16x32_bf16(a, b1, acc[1], 0, 0, 0);
    }
  }

  if (ACT == 1) {
#pragma unroll
    for (int j = 0; j < 2; ++j) {
      const int n = n0 + wn * 32 + j * 16 + l16;
      const int mB = m0 + wm * 16 + quad * 4;
      const float bv = bias[n];
#pragma unroll
      for (int r = 0; r < 4; ++r)
        xbf[(long)g * NN * HH + (long)(mB + r) * HH + n] =
            f2bf(fmaxf(acc[j][r] + bv, 0.f));
    }
  } else {
    const int mB0 = m0 + wm * 16 + quad * 4;
    float zv[2][4];
#pragma unroll
    for (int j = 0; j < 2; ++j) {
      const int n = n0 + wn * 32 + j * 16 + l16;
      const float bv = bias[n];
#pragma unroll
      for (int r = 0; r < 4; ++r) {
        const long idx = (long)g * NN * HH + (long)(mB0 + r) * HH + n;
        zv[j][r] = tanhf(acc[j][r] + bv) + bf2f(h0bf[idx]);
      }
    }
    for (int b = 0; b < BB; ++b) {
      if (gidx[b] != g) continue;  // block-uniform branch
      const float invd = 1.f / denom[b];
      float m4[4];
#pragma unroll
      for (int r = 0; r < 4; ++r) m4[r] = fmask[b * NN + mB0 + r];
#pragma unroll
      for (int j = 0; j < 2; ++j) {
        float p = m4[0] * zv[j][0] + m4[1] * zv[j][1] + m4[2] * zv[j][2] +
                  m4[3] * zv[j][3];
        p += __shfl_xor(p, 16);
        p += __shfl_xor(p, 32);
        if (quad == 0) {
          const int n = n0 + wn * 32 + j * 16 + l16;
          atomicAdd(&out[b * HH + n], p * invd);
        }
      }
    }
  }
}

extern "C" void kernel_launch(void* const* d_in, const int* in_sizes, int n_in,
                              void* d_out, int out_size, void* d_ws,
                              size_t ws_size, hipStream_t stream) {
  (void)in_sizes; (void)n_in; (void)out_size; (void)ws_size;
  const float* batch_xs = (const float*)d_in[0];
  const float* batch_as = (const float*)d_in[1];
  const float* w_in = (const float*)d_in[2];
  const float* b_in = (const float*)d_in[3];
  const float* gcn_w = (const float*)d_in[4];
  const float* gcn_b = (const float*)d_in[5];
  const int* graph_idx = (const int*)d_in[6];
  const void* cp_mask = d_in[7];
  float* out = (float*)d_out;

  char* p = (char*)d_ws;
  unsigned short* Abf = (unsigned short*)p;  p += (long)G * NN * NN * 2;
  unsigned short* gwT = (unsigned short*)p;  p += (long)LL * HH * HH * 2;
  unsigned short* xbf = (unsigned short*)p;  p += (long)G * NN * HH * 2;
  unsigned short* h0bf = (unsigned short*)p; p += (long)G * NN * HH * 2;
  unsigned short* yTa = (unsigned short*)p;  p += (long)G * HH * NN * 2;
  unsigned short* yTb = (unsigned short*)p;  p += (long)G * HH * NN * 2;
  float* fmask = (float*)p;                  p += (long)BB * NN * 4;
  float* denom = (float*)p;                  p += BB * 4;

  pre_kernel<<<1377, 256, 0, stream>>>(batch_as, Abf, batch_xs, w_in, b_in,
                                       xbf, h0bf, gcn_w, gwT, cp_mask, fmask,
                                       denom, out);

  // y0 = x0 @ W0
  g1_kernel<<<dim3(4, 16, G), 256, 0, stream>>>(xbf, gwT, yTa);

  for (int l = 0; l < LL; ++l) {
    const unsigned short* ycur = (l & 1) ? yTb : yTa;
    unsigned short* ynext = (l & 1) ? yTa : yTb;
    if (l < LL - 1) {
      g2_kernel<1><<<dim3(4, 32, G), 256, 0, stream>>>(
          Abf, ycur, gcn_b + (long)l * HH, nullptr, xbf, nullptr, nullptr,
          nullptr, nullptr);
      g1_kernel<<<dim3(4, 16, G), 256, 0, stream>>>(
          xbf, gwT + (long)(l + 1) * HH * HH, ynext);
    } else {
      g2_kernel<0><<<dim3(4, 32, G), 256, 0, stream>>>(
          Abf, ycur, gcn_b + (long)l * HH, h0bf, nullptr, fmask, denom,
          graph_idx, out);
    }
  }
}

// Round 8
// 148.440 us; speedup vs baseline: 1.4272x; 1.0064x over previous
//
#include <hip/hip_runtime.h>
#include <math.h>

#define G 4
#define NN 1024
#define FF 256
#define HH 256
#define BB 32
#define LL 4

typedef __attribute__((ext_vector_type(8))) short short8;
typedef __attribute__((ext_vector_type(8))) unsigned short ushort8;
typedef __attribute__((ext_vector_type(4))) unsigned short ushort4v;
typedef __attribute__((ext_vector_type(4))) float floatx4;

__device__ inline unsigned short f2bf(float f) {
  union { float f; unsigned u; } x; x.f = f;
  unsigned r = x.u + 0x7fffu + ((x.u >> 16) & 1u);  // RNE
  return (unsigned short)(r >> 16);
}
__device__ inline float bf2f(unsigned short u) {
  union { unsigned u; float f; } x; x.u = (unsigned)u << 16;
  return x.f;
}

// ---- in tile: x0 = relu(X @ w_in + b_in) -> xbf + h0bf (both bf16 [m][n])
// [R0-verified]
__device__ void in_tile(int job, const float* __restrict__ X,
                        const float* __restrict__ w_in,
                        const float* __restrict__ b_in,
                        unsigned short* __restrict__ xbf,
                        unsigned short* __restrict__ h0bf, unsigned short* As,
                        unsigned short* Bs, int t) {
  const int nt_ = job & 3, mt = (job >> 2) & 15, g = job >> 6;
  const int m0 = mt * 64, n0 = nt_ * 64;
  const int lane = t & 63, w = t >> 6;
  const int wm = w & 1, wn = w >> 1;
  const int l16 = lane & 15, quad = lane >> 4;

  floatx4 acc[2][2];
#pragma unroll
  for (int i = 0; i < 2; ++i)
#pragma unroll
    for (int j = 0; j < 2; ++j) acc[i][j] = (floatx4){0.f, 0.f, 0.f, 0.f};

  for (int tt = 0; tt < 4; ++tt) {
    const int kb = tt * 64;
    __syncthreads();
#pragma unroll
    for (int i = 0; i < 2; ++i) {
      const int q = t + i * 256;
      const int row = q >> 3, c8 = q & 7;
      const float* Af =
          X + (long)g * NN * FF + (long)(m0 + row) * FF + kb + c8 * 8;
      float4 f0 = *(const float4*)Af;
      float4 f1 = *(const float4*)(Af + 4);
      ushort8 v;
      v[0] = f2bf(f0.x); v[1] = f2bf(f0.y); v[2] = f2bf(f0.z); v[3] = f2bf(f0.w);
      v[4] = f2bf(f1.x); v[5] = f2bf(f1.y); v[6] = f2bf(f1.z); v[7] = f2bf(f1.w);
      *(ushort8*)&As[row * 72 + c8 * 8] = v;
    }
    {  // w_in fp32 [k][n] -> Bs[n][k] (LDS transpose)
      const int row = t >> 2;
      const int c0 = (t & 3) * 16;
#pragma unroll
      for (int j = 0; j < 4; ++j) {
        float4 f = *(const float4*)&w_in[(long)(kb + row) * HH + n0 + c0 + j * 4];
        Bs[(c0 + j * 4 + 0) * 72 + row] = f2bf(f.x);
        Bs[(c0 + j * 4 + 1) * 72 + row] = f2bf(f.y);
        Bs[(c0 + j * 4 + 2) * 72 + row] = f2bf(f.z);
        Bs[(c0 + j * 4 + 3) * 72 + row] = f2bf(f.w);
      }
    }
    __syncthreads();
#pragma unroll
    for (int kk = 0; kk < 64; kk += 32) {
      const int ko = kk + quad * 8;
      short8 a0 = *(const short8*)&As[(wm * 32 + l16) * 72 + ko];
      short8 a1 = *(const short8*)&As[(wm * 32 + 16 + l16) * 72 + ko];
      short8 b0 = *(const short8*)&Bs[(wn * 32 + l16) * 72 + ko];
      short8 b1 = *(const short8*)&Bs[(wn * 32 + 16 + l16) * 72 + ko];
      acc[0][0] = __builtin_amdgcn_mfma_f32_16x16x32_bf16(a0, b0, acc[0][0], 0, 0, 0);
      acc[0][1] = __builtin_amdgcn_mfma_f32_16x16x32_bf16(a0, b1, acc[0][1], 0, 0, 0);
      acc[1][0] = __builtin_amdgcn_mfma_f32_16x16x32_bf16(a1, b0, acc[1][0], 0, 0, 0);
      acc[1][1] = __builtin_amdgcn_mfma_f32_16x16x32_bf16(a1, b1, acc[1][1], 0, 0, 0);
    }
  }

#pragma unroll
  for (int i = 0; i < 2; ++i) {
#pragma unroll
    for (int j = 0; j < 2; ++j) {
      const int n = n0 + wn * 32 + j * 16 + l16;
      const int mB = m0 + wm * 32 + i * 16 + quad * 4;
      const float bv = b_in[n];
#pragma unroll
      for (int r = 0; r < 4; ++r) {
        const unsigned short pv = f2bf(fmaxf(acc[i][j][r] + bv, 0.f));
        xbf[(long)g * NN * HH + (long)(mB + r) * HH + n] = pv;
        h0bf[(long)g * NN * HH + (long)(mB + r) * HH + n] = pv;
      }
    }
  }
}

// ---- misc jobs [R0-verified] ----
__device__ void mask_job(int b, const void* __restrict__ cp_mask,
                         float* __restrict__ fmask, float* __restrict__ denom,
                         int t) {
  const unsigned char* bytes = (const unsigned char*)cp_mask;
  __shared__ int fmt;
  __shared__ float red[256];
  if (t == 0) {
    int any = 0;
    for (int i = 0; i < 256; ++i)
      if ((i & 3) && bytes[i]) any = 1;
    fmt = any ? 0 : 1;
  }
  __syncthreads();
  float cnt = 0.f;
  for (int n = t; n < NN; n += 256) {
    float v;
    if (fmt)
      v = ((const int*)cp_mask)[b * NN + n] ? 1.f : 0.f;
    else
      v = bytes[b * NN + n] ? 1.f : 0.f;
    fmask[b * NN + n] = v;
    cnt += v;
  }
  red[t] = cnt;
  __syncthreads();
  for (int s = 128; s > 0; s >>= 1) {
    if (t < s) red[t] += red[t + s];
    __syncthreads();
  }
  if (t == 0) denom[b] = fmaxf(red[0], 1.f);
}

__device__ void gw_job(int j, const float* __restrict__ gcn_w,
                       unsigned short* __restrict__ gwT, int t) {
  const int l = j >> 4, r0 = (j & 15) * 16;
  const float* src = gcn_w + (long)l * HH * HH;
  unsigned short* dst = gwT + (long)l * HH * HH;
  unsigned short vv[16];
#pragma unroll
  for (int rr = 0; rr < 16; ++rr) vv[rr] = f2bf(src[(long)(r0 + rr) * HH + t]);
  *(ushort8*)&dst[(long)t * HH + r0] = *(ushort8*)&vv[0];
  *(ushort8*)&dst[(long)t * HH + r0 + 8] = *(ushort8*)&vv[8];
}

// ---------------------------------------------------------------------------
// pre_kernel [R0-verified]: [0,1024) A fp32->bf16 (16 el/thr);
// [1024,1280) input GEMM; [1280,1344) gwT; [1344,1376) mask; 1376 zero-out.
// ---------------------------------------------------------------------------
__global__ __launch_bounds__(256) void pre_kernel(
    const float* __restrict__ batch_as, unsigned short* __restrict__ Abf,
    const float* __restrict__ batch_xs, const float* __restrict__ w_in,
    const float* __restrict__ b_in, unsigned short* __restrict__ xbf,
    unsigned short* __restrict__ h0bf, const float* __restrict__ gcn_w,
    unsigned short* __restrict__ gwT, const void* __restrict__ cp_mask,
    float* __restrict__ fmask, float* __restrict__ denom,
    float* __restrict__ out) {
  __shared__ __align__(16) unsigned short As[64 * 72];
  __shared__ __align__(16) unsigned short Bs[64 * 72];
  const int b = blockIdx.x, t = threadIdx.x;
  if (b < 1024) {
    const long idx = ((long)b * 256 + t) * 16;
#pragma unroll
    for (int h = 0; h < 2; ++h) {
      float4 f0 = *(const float4*)&batch_as[idx + h * 8];
      float4 f1 = *(const float4*)&batch_as[idx + h * 8 + 4];
      ushort8 v;
      v[0] = f2bf(f0.x); v[1] = f2bf(f0.y); v[2] = f2bf(f0.z); v[3] = f2bf(f0.w);
      v[4] = f2bf(f1.x); v[5] = f2bf(f1.y); v[6] = f2bf(f1.z); v[7] = f2bf(f1.w);
      *(ushort8*)&Abf[idx + h * 8] = v;
    }
  } else if (b < 1280) {
    in_tile(b - 1024, batch_xs, w_in, b_in, xbf, h0bf, As, Bs, t);
  } else if (b < 1344) {
    gw_job(b - 1280, gcn_w, gwT, t);
  } else if (b < 1376) {
    mask_job(b - 1344, cp_mask, fmask, denom, t);
  } else {
    for (int i = 0; i < 32; ++i) out[i * 256 + t] = 0.f;
  }
}

// ---------------------------------------------------------------------------
// Unified GEMM: 32x64 tile, 512 threads (8 waves, 2x4 wm x wn), BK=128.
// grid (4, 32, G) = 512 blocks x 8 waves = 16 waves/CU (2x the old g2,
// 4x the old g1).  Each wave owns ONE 16x16 output frag -> 1 MFMA per
// 32-k step; fragment mapping and k-accumulation order identical to the
// verified kernels (bit-identical numerics).
// EPI 0: xout = relu(C + bias)  (row-major xbf)
// EPI 1: xout[n][m] = bf16(C)   (transposed yT store)
// EPI 2: tanh + residual + masked mean -> atomics into out
// ---------------------------------------------------------------------------
template <int EPI, int KSTEPS>
__global__ __launch_bounds__(512) void gemm_kernel(
    const unsigned short* __restrict__ Abase, int sA, long gsA,
    const unsigned short* __restrict__ Bbase, int sB, long gsB,
    const float* __restrict__ bias, const unsigned short* __restrict__ h0bf,
    unsigned short* __restrict__ xout, const float* __restrict__ fmask,
    const float* __restrict__ denom, const int* __restrict__ gidx,
    float* __restrict__ out) {
  __shared__ __align__(16) unsigned short As[32 * 136];
  __shared__ __align__(16) unsigned short Bs[64 * 136];
  const int n0 = blockIdx.x * 64;
  const int m0 = blockIdx.y * 32;
  const int g = blockIdx.z;
  const int t = threadIdx.x;
  const int lane = t & 63, w = t >> 6;
  const int wm = w & 1, wn = w >> 1;  // 2 x 4 wave grid
  const int l16 = lane & 15, quad = lane >> 4;

  const unsigned short* Ap = Abase + (long)g * gsA + (long)m0 * sA;
  const unsigned short* Bp = Bbase + (long)g * gsB + (long)n0 * sB;

  ushort8 pa, pb[2];
  auto load_tile = [&](int tt) {
    const int kb = tt * 128;
    {  // A: 32 rows x 128 k = 512 chunks, 1/thread
      const int row = t >> 4, c8 = t & 15;
      pa = *(const ushort8*)&Ap[(long)row * sA + kb + c8 * 8];
    }
#pragma unroll
    for (int i = 0; i < 2; ++i) {  // B: 64 rows x 128 k = 1024 chunks
      const int q = t + i * 512;
      const int row = q >> 4, c8 = q & 15;
      pb[i] = *(const ushort8*)&Bp[(long)row * sB + kb + c8 * 8];
    }
  };
  auto store_tile = [&]() {
    {
      const int row = t >> 4, c8 = t & 15;
      *(ushort8*)&As[row * 136 + c8 * 8] = pa;
    }
#pragma unroll
    for (int i = 0; i < 2; ++i) {
      const int q = t + i * 512;
      const int row = q >> 4, c8 = q & 15;
      *(ushort8*)&Bs[row * 136 + c8 * 8] = pb[i];
    }
  };

  floatx4 acc = (floatx4){0.f, 0.f, 0.f, 0.f};

  load_tile(0);
  for (int tt = 0; tt < KSTEPS; ++tt) {
    __syncthreads();
    store_tile();
    __syncthreads();
    if (tt + 1 < KSTEPS) load_tile(tt + 1);
#pragma unroll
    for (int kk = 0; kk < 128; kk += 32) {
      const int ko = kk + quad * 8;
      short8 a = *(const short8*)&As[(wm * 16 + l16) * 136 + ko];
      short8 b = *(const short8*)&Bs[(wn * 16 + l16) * 136 + ko];
      acc = __builtin_amdgcn_mfma_f32_16x16x32_bf16(a, b, acc, 0, 0, 0);
    }
  }

  const int n = n0 + wn * 16 + l16;
  const int mB = m0 + wm * 16 + quad * 4;
  if (EPI == 0) {
    const float bv = bias[n];
#pragma unroll
    for (int r = 0; r < 4; ++r)
      xout[(long)g * NN * HH + (long)(mB + r) * HH + n] =
          f2bf(fmaxf(acc[r] + bv, 0.f));
  } else if (EPI == 1) {
    ushort4v pv;
#pragma unroll
    for (int r = 0; r < 4; ++r) pv[r] = f2bf(acc[r]);
    *(ushort4v*)&xout[(long)g * HH * NN + (long)n * NN + mB] = pv;
  } else {
    const float bv = bias[n];
    float zv[4];
#pragma unroll
    for (int r = 0; r < 4; ++r) {
      const long idx = (long)g * NN * HH + (long)(mB + r) * HH + n;
      zv[r] = tanhf(acc[r] + bv) + bf2f(h0bf[idx]);
    }
    for (int b = 0; b < BB; ++b) {
      if (gidx[b] != g) continue;  // block-uniform branch
      const float invd = 1.f / denom[b];
      float m4[4];
#pragma unroll
      for (int r = 0; r < 4; ++r) m4[r] = fmask[b * NN + mB + r];
      float p = m4[0] * zv[0] + m4[1] * zv[1] + m4[2] * zv[2] + m4[3] * zv[3];
      p += __shfl_xor(p, 16);  // sum over quad bit 0
      p += __shfl_xor(p, 32);  // sum over quad bit 1
      if (quad == 0) atomicAdd(&out[b * HH + n], p * invd);
    }
  }
}

extern "C" void kernel_launch(void* const* d_in, const int* in_sizes, int n_in,
                              void* d_out, int out_size, void* d_ws,
                              size_t ws_size, hipStream_t stream) {
  (void)in_sizes; (void)n_in; (void)out_size; (void)ws_size;
  const float* batch_xs = (const float*)d_in[0];
  const float* batch_as = (const float*)d_in[1];
  const float* w_in = (const float*)d_in[2];
  const float* b_in = (const float*)d_in[3];
  const float* gcn_w = (const float*)d_in[4];
  const float* gcn_b = (const float*)d_in[5];
  const int* graph_idx = (const int*)d_in[6];
  const void* cp_mask = d_in[7];
  float* out = (float*)d_out;

  char* p = (char*)d_ws;
  unsigned short* Abf = (unsigned short*)p;  p += (long)G * NN * NN * 2;
  unsigned short* gwT = (unsigned short*)p;  p += (long)LL * HH * HH * 2;
  unsigned short* xbf = (unsigned short*)p;  p += (long)G * NN * HH * 2;
  unsigned short* h0bf = (unsigned short*)p; p += (long)G * NN * HH * 2;
  unsigned short* yTa = (unsigned short*)p;  p += (long)G * HH * NN * 2;
  unsigned short* yTb = (unsigned short*)p;  p += (long)G * HH * NN * 2;
  float* fmask = (float*)p;                  p += (long)BB * NN * 4;
  float* denom = (float*)p;                  p += BB * 4;

  pre_kernel<<<1377, 256, 0, stream>>>(batch_as, Abf, batch_xs, w_in, b_in,
                                       xbf, h0bf, gcn_w, gwT, cp_mask, fmask,
                                       denom, out);

  const dim3 gg(4, 32, G);
  // y0 = x0 @ W0   (A = xbf, stride HH; B = W0^T, stride HH, no g-offset)
  gemm_kernel<1, 2><<<gg, 512, 0, stream>>>(
      xbf, HH, (long)NN * HH, gwT, HH, 0L, nullptr, nullptr, yTa, nullptr,
      nullptr, nullptr, nullptr);

  for (int l = 0; l < LL; ++l) {
    unsigned short* ycur = (l & 1) ? yTb : yTa;
    unsigned short* ynext = (l & 1) ? yTa : yTb;
    if (l < LL - 1) {
      // x_{l+1} = relu(A @ y_l + b_l)
      gemm_kernel<0, 8><<<gg, 512, 0, stream>>>(
          Abf, NN, (long)NN * NN, ycur, NN, (long)HH * NN, gcn_b + (long)l * HH,
          nullptr, xbf, nullptr, nullptr, nullptr, nullptr);
      // y_{l+1} = x_{l+1} @ W_{l+1}
      gemm_kernel<1, 2><<<gg, 512, 0, stream>>>(
          xbf, HH, (long)NN * HH, gwT + (long)(l + 1) * HH * HH, HH, 0L,
          nullptr, nullptr, ynext, nullptr, nullptr, nullptr, nullptr);
    } else {
      // final: tanh(A @ y3 + b3) + h0, masked mean
      gemm_kernel<2, 8><<<gg, 512, 0, stream>>>(
          Abf, NN, (long)NN * NN, ycur, NN, (long)HH * NN, gcn_b + (long)l * HH,
          h0bf, nullptr, fmask, denom, graph_idx, out);
    }
  }
}